// Round 12
// baseline (159.962 us; speedup 1.0000x reference)
//
#include <hip/hip_runtime.h>
#include <hip/hip_bf16.h>

#define NDIM  4096
#define MROWS 8192
#define PREAL 969
#define KP    1024   // 16 * 64
#define NT    16
#define NWFOLD 1024  // wfold blocks: 16 x 64

typedef unsigned short u16;
typedef __attribute__((ext_vector_type(8))) __bf16 bf16x8;
typedef __attribute__((ext_vector_type(8))) u16 u16x8;
typedef __attribute__((ext_vector_type(4))) float f32x4;

__device__ __forceinline__ u16 bf16rne(float f) {
  unsigned int u = __builtin_bit_cast(unsigned int, f);
  u += 0x7fffu + ((u >> 16) & 1u);
  return (u16)(u >> 16);
}

// -------- compile-time multiset table: TBL.v[p] = (i<<10)|(j<<5)|k, idx 16 = "1"; -1 = pad --------
struct Tbl { int v[KP]; };
constexpr Tbl make_table() {
  Tbl t{};
  for (int p = 0; p < KP; ++p) t.v[p] = -1;
  int p = 0;
  t.v[p++] = (16 << 10) | (16 << 5) | 16;
  for (int i = 0; i < 16; ++i) t.v[p++] = (i << 10) | (16 << 5) | 16;
  for (int i = 0; i < 16; ++i)
    for (int j = i; j < 16; ++j) t.v[p++] = (i << 10) | (j << 5) | 16;
  for (int i = 0; i < 16; ++i)
    for (int j = i; j < 16; ++j)
      for (int k = j; k < 16; ++k) t.v[p++] = (i << 10) | (j << 5) | k;
  return t;
}
__device__ constexpr Tbl TBL = make_table();

// -------- merged prep: blocks [0,NWFOLD) fold W; blocks [NWFOLD, NWFOLD+MROWS) build features --------
__global__ void prep_kernel(const float* __restrict__ z, const float* __restrict__ W,
                            const float* __restrict__ bias,
                            u16* __restrict__ xb, u16* __restrict__ wfbt) {
  __shared__ float tile[64][65];
  __shared__ float zs[17];
  const int bx = blockIdx.x;
  const int tid = threadIdx.x;

  if (bx < NWFOLD) {
    const int p0 = (bx & 15) * 64;
    const int d0 = (bx >> 4) * 64;
    const int d4 = (tid & 15) * 4;
    const int rb = tid >> 4;
    const int dd = d0 + d4;
#pragma unroll
    for (int pp = 0; pp < 4; ++pp) {
      const int r = pp * 16 + rb;
      const int p = p0 + r;
      const int enc = TBL.v[p];
      f32x4 v = {0.f, 0.f, 0.f, 0.f};
      if (enc >= 0) {
        const int i = enc >> 10, j = (enc >> 5) & 31, k = enc & 31;
        if (k == 16) {
          if (j == 16) {
            if (i == 16) {
              v = *reinterpret_cast<const f32x4*>(W + dd);
              f32x4 bb = *reinterpret_cast<const f32x4*>(bias + dd);
              v.x += bb.x; v.y += bb.y; v.z += bb.z; v.w += bb.w;
            } else {
              v = *reinterpret_cast<const f32x4*>(W + (size_t)(1 + i) * NDIM + dd);
            }
          } else {
            v = *reinterpret_cast<const f32x4*>(W + (size_t)(17 + i * 16 + j) * NDIM + dd);
            if (i != j) {
              f32x4 w2 = *reinterpret_cast<const f32x4*>(W + (size_t)(17 + j * 16 + i) * NDIM + dd);
              v.x += w2.x; v.y += w2.y; v.z += w2.z; v.w += w2.w;
            }
          }
        } else {
          int rows[6];
          int nr = 0;
          rows[nr++] = 273 + i * 256 + j * 16 + k;
          if (i == j && j == k) {
          } else if (i == j) {
            rows[nr++] = 273 + i * 256 + k * 16 + i;
            rows[nr++] = 273 + k * 256 + i * 16 + i;
          } else if (j == k) {
            rows[nr++] = 273 + j * 256 + i * 16 + j;
            rows[nr++] = 273 + j * 256 + j * 16 + i;
          } else {
            rows[nr++] = 273 + i * 256 + k * 16 + j;
            rows[nr++] = 273 + j * 256 + i * 16 + k;
            rows[nr++] = 273 + j * 256 + k * 16 + i;
            rows[nr++] = 273 + k * 256 + i * 16 + j;
            rows[nr++] = 273 + k * 256 + j * 16 + i;
          }
          v = *reinterpret_cast<const f32x4*>(W + (size_t)rows[0] * NDIM + dd);
          for (int s = 1; s < nr; ++s) {
            f32x4 w2 = *reinterpret_cast<const f32x4*>(W + (size_t)rows[s] * NDIM + dd);
            v.x += w2.x; v.y += w2.y; v.z += w2.z; v.w += w2.w;
          }
        }
      }
#pragma unroll
      for (int jj = 0; jj < 4; ++jj) tile[r][d4 + jj] = v[jj];
    }
    __syncthreads();
#pragma unroll
    for (int round = 0; round < 2; ++round) {
      const int v = round * 256 + tid;
      const int d = v >> 3;
      const int tg = v & 7;
      u16x8 pack;
#pragma unroll
      for (int e = 0; e < 8; ++e) pack[e] = bf16rne(tile[tg * 8 + e][d]);
      *reinterpret_cast<u16x8*>(wfbt + (size_t)(d0 + d) * KP + p0 + tg * 8) = pack;
    }
  } else {
    const int row = bx - NWFOLD;
    if (tid < 16) zs[tid] = z[row * 16 + tid];
    if (tid == 16) zs[16] = 1.0f;
    __syncthreads();
    u16* xrow = xb + (size_t)row * KP;
    for (int g = tid; g < KP / 8; g += 256) {
      u16x8 pack;
#pragma unroll
      for (int e = 0; e < 8; ++e) {
        const int enc = TBL.v[g * 8 + e];
        float v = 0.0f;
        if (enc >= 0) v = zs[enc >> 10] * (zs[(enc >> 5) & 31] * zs[enc & 31]);
        pack[e] = bf16rne(v);
      }
      *reinterpret_cast<u16x8*>(xrow + g * 8) = pack;
    }
  }
}

// ------- 256x256 GEMM, R9 fence chain + register-pipelined QUADs (read-ahead >= 1 phase) -------
#define GLOAD(gp, lp)                                                                     \
  __builtin_amdgcn_global_load_lds((const __attribute__((address_space(1))) unsigned int*)(gp), \
                                   (__attribute__((address_space(3))) unsigned int*)(lp), 16, 0, 0)

__device__ __forceinline__ void bar() {
  asm volatile("" ::: "memory");
  __builtin_amdgcn_s_barrier();
  asm volatile("" ::: "memory");
}

#define VM4 asm volatile("s_waitcnt vmcnt(4)" ::: "memory")
#define VM1 asm volatile("s_waitcnt vmcnt(1)" ::: "memory")
#define VM0 asm volatile("s_waitcnt vmcnt(0)" ::: "memory")

__global__ __launch_bounds__(512, 2) void gemm_kernel(const u16* __restrict__ xb,
                                                      const u16* __restrict__ wbt,
                                                      float* __restrict__ out) {
  __shared__ u16 lds[2 * 32768];  // 128 KiB

  // XCD swizzle, chunked 4Mx8N (R6-validated)
  const int bid  = blockIdx.x;
  const int xcd  = bid & 7;
  const int idx  = bid >> 3;
  const int mtl  = (idx >> 3) & 3;
  const int ntl  = (idx & 7) | ((idx >> 5) << 3);
  const int brow = (xcd * 4 + mtl) * 256;
  const int bcol = ntl * 256;

  const int tid  = threadIdx.x;
  const int lane = tid & 63;
  const int wid  = tid >> 6;
  const int wr   = wid >> 2;
  const int wc   = wid & 3;
  const int f    = lane & 15;
  const int q    = lane >> 4;
  const int f7   = f & 7;

  // staging geometry (R9): quarters matched to phase read-sets
  const int lr = lane >> 3;
  const int swzc = ((lane & 7) ^ lr) * 8;
  const u16* gA = xb  + (size_t)(brow + lr) * KP + swzc;
  const u16* gB = wbt + (size_t)(bcol + lr) * KP + swzc;
  const int aB0 = (wid >> 2) * 128 + (wid & 3) * 16;  // Ah0 base; Ah1 = +64
  const int bB0 = (wid >> 1) * 64 + (wid & 1) * 16;   // Bh0 base; Bh1 = +32

#define STGQ(gptr, region, rb, U) do {                                               \
    GLOAD((gptr) + (size_t)(rb) * KP + (U) * 64, (region) + (rb) * 64);              \
    GLOAD((gptr) + (size_t)((rb) + 8) * KP + (U) * 64, (region) + ((rb) + 8) * 64);  \
  } while (0)

#define RD_A(mi, kk) (*reinterpret_cast<const bf16x8*>(bufA + (wr * 128 + (mi) * 16 + f) * 64 + (((kk) * 4 + q) ^ f7) * 8))
#define RD_B(ni, kk) (*reinterpret_cast<const bf16x8*>(bufB + (wc * 64 + (ni) * 16 + f) * 64 + (((kk) * 4 + q) ^ f7) * 8))

#define RDA_TO(DST, MOFF) do {                                                       \
    _Pragma("unroll") for (int _i = 0; _i < 4; ++_i) {                               \
      DST[_i][0] = RD_A((MOFF) + _i, 0); DST[_i][1] = RD_A((MOFF) + _i, 1); }        \
  } while (0)
#define RDB_TO(DST, NOFF) do {                                                       \
    _Pragma("unroll") for (int _i = 0; _i < 2; ++_i) {                               \
      DST[_i][0] = RD_B((NOFF) + _i, 0); DST[_i][1] = RD_B((NOFF) + _i, 1); }        \
  } while (0)

#define QUADX(MOFF, NOFF, AF, BF) do {                                               \
    __builtin_amdgcn_s_setprio(1);                                                   \
    _Pragma("unroll") for (int _m = 0; _m < 4; ++_m)                                 \
    _Pragma("unroll") for (int _n = 0; _n < 2; ++_n)                                 \
    _Pragma("unroll") for (int _k = 0; _k < 2; ++_k)                                 \
      acc[(MOFF) + _m][(NOFF) + _n] = __builtin_amdgcn_mfma_f32_16x16x32_bf16(       \
          AF[_m][_k], BF[_n][_k], acc[(MOFF) + _m][(NOFF) + _n], 0, 0, 0);           \
    __builtin_amdgcn_s_setprio(0);                                                   \
  } while (0)

// steady tile t (1..14): reads (cA,cB); stages tile t+1 into (nA,nB); quadrant (4,0)
// of tile t-1 is DEFERRED to this tile's ph1 (operands in regs A1, B0U).
// Fence chain = R9 (VM4 @ ph1/ph2/ph4): confirms Bh1(t)@ph1, Ah1(t)@ph2, a0b0(t+1)@ph4.
#define TILE_STD(cA, cB, nA, nB, U, B0R, B0U) do {                                   \
    bufA = (cA); bufB = (cB);                                                        \
    RDA_TO(A0, 0); RDB_TO(B0R, 0); STGQ(gA, (nA), aB0, (U));                         \
    QUADX(4, 0, A1, B0U); VM4; bar();                                                \
    RDB_TO(B1, 2);        STGQ(gB, (nB), bB0, (U));                                  \
    QUADX(0, 0, A0, B0R); VM4; bar();                                                \
    RDA_TO(A1, 4);        STGQ(gB, (nB), bB0 + 32, (U));                             \
    QUADX(0, 2, A0, B1);  bar();                                                     \
                          STGQ(gA, (nA), aB0 + 64, (U));                             \
    QUADX(4, 2, A1, B1);  VM4; bar();                                                \
  } while (0)

  f32x4 acc[8][4] = {};
  bf16x8 A0[4][2], A1[4][2], B0a[2][2], B0b[2][2], B1[2][2];
  const u16 *bufA, *bufB;

  u16* b0A = lds;            u16* b0B = lds + 16384;
  u16* b1A = lds + 32768;    u16* b1B = b1A + 16384;

  // prologue: stage tile0's 4 quarters; VM4 -> Ah0(0),Bh0(0) resident
  STGQ(gA, b0A, aB0, 0); STGQ(gB, b0B, bB0, 0);
  STGQ(gB, b0B, bB0 + 32, 0); STGQ(gA, b0A, aB0 + 64, 0);
  VM4; bar();

  // ---- tile 0 (reads buf0, stages tile1 -> buf1); no deferred QUAD at ph1 ----
  bufA = b0A; bufB = b0B;
  RDA_TO(A0, 0); RDB_TO(B0a, 0); STGQ(gA, b1A, aB0, 1);
  VM4; bar();
  RDB_TO(B1, 2);        STGQ(gB, b1B, bB0, 1);
  QUADX(0, 0, A0, B0a); VM4; bar();
  RDA_TO(A1, 4);        STGQ(gB, b1B, bB0 + 32, 1);
  QUADX(0, 2, A0, B1);  bar();
                        STGQ(gA, b1A, aB0 + 64, 1);
  QUADX(4, 2, A1, B1);  VM4; bar();

  // ---- tiles 1..14 (odd reads buf1 -> B0b; even reads buf0 -> B0a) ----
  for (int t = 1; t < NT - 1; t += 2) {
    TILE_STD(b1A, b1B, b0A, b0B, t + 1, B0b, B0a);   // odd tile t
    TILE_STD(b0A, b0B, b1A, b1B, t + 2, B0a, B0b);   // even tile t+1
  }

  // ---- tile 15 (reads buf1, no staging): fences VM1@ph1, VM0@ph2 ----
  bufA = b1A; bufB = b1B;
  RDA_TO(A0, 0); RDB_TO(B0b, 0);
  QUADX(4, 0, A1, B0a); VM1; bar();    // outstanding {Bh1(15),Ah1(15)} -> drain Bh1
  RDB_TO(B1, 2);
  QUADX(0, 0, A0, B0b); VM0; bar();    // drain Ah1(15)
  RDA_TO(A1, 4);
  QUADX(0, 2, A0, B1);  bar();
  QUADX(4, 2, A1, B1);
  QUADX(4, 0, A1, B0b);                // deferred final quadrant (register-only)

  // epilogue: plain cached stores (R10 lesson: nontemporal 4B stores amplify writes)
  const int r0 = brow + wr * 128 + q * 4;
  const int c0 = bcol + wc * 64 + f;
#pragma unroll
  for (int mi = 0; mi < 8; ++mi)
#pragma unroll
    for (int ni = 0; ni < 4; ++ni) {
#pragma unroll
      for (int j = 0; j < 4; ++j)
        out[(size_t)(r0 + mi * 16 + j) * NDIM + (c0 + ni * 16)] = acc[mi][ni][j];
    }
}

// ---------------- fallback (ws too small): correct fp32 path on raw features ----------------
__global__ void fallback_kernel(const float* __restrict__ z, const float* __restrict__ W,
                                const float* __restrict__ bias, float* __restrict__ out) {
  __shared__ float feat[4369];
  const int row = blockIdx.x;
  const int tid = threadIdx.x;
  for (int t = tid; t < 4369; t += 256) {
    float v;
    if (t == 0) v = 1.0f;
    else if (t < 17) v = z[row * 16 + t - 1];
    else if (t < 273) { int u = t - 17; v = z[row * 16 + (u >> 4)] * z[row * 16 + (u & 15)]; }
    else { int u = t - 273; v = z[row * 16 + ((u >> 8) & 15)] * (z[row * 16 + ((u >> 4) & 15)] * z[row * 16 + (u & 15)]); }
    feat[t] = v;
  }
  __syncthreads();
  float acc[16];
#pragma unroll
  for (int j = 0; j < 16; ++j) acc[j] = bias[tid + 256 * j];
  for (int t = 0; t < 4369; ++t) {
    const float fv = feat[t];
    const float* wrow = W + (size_t)t * NDIM;
#pragma unroll
    for (int j = 0; j < 16; ++j) acc[j] = fmaf(fv, wrow[tid + 256 * j], acc[j]);
  }
  float* orow = out + (size_t)row * NDIM;
#pragma unroll
  for (int j = 0; j < 16; ++j) orow[tid + 256 * j] = acc[j];
}

extern "C" void kernel_launch(void* const* d_in, const int* in_sizes, int n_in,
                              void* d_out, int out_size, void* d_ws, size_t ws_size,
                              hipStream_t stream) {
  const float* z = (const float*)d_in[0];
  const float* W = (const float*)d_in[1];
  const float* b = (const float*)d_in[2];
  float* out = (float*)d_out;

  const size_t xb_elems  = (size_t)MROWS * KP;
  const size_t wbt_elems = (size_t)NDIM * KP;
  const size_t need = (xb_elems + wbt_elems) * sizeof(u16);

  if (ws_size >= need) {
    u16* xb  = (u16*)d_ws;
    u16* wbt = xb + xb_elems;
    prep_kernel<<<NWFOLD + MROWS, 256, 0, stream>>>(z, W, b, xb, wbt);
    gemm_kernel<<<(MROWS / 256) * (NDIM / 256), 512, 0, stream>>>(xb, wbt, out);
  } else {
    fallback_kernel<<<MROWS, 256, 0, stream>>>(z, W, b, out);
  }
}

// Round 13
// 104.187 us; speedup vs baseline: 1.5353x; 1.5353x over previous
//
#include <hip/hip_runtime.h>
#include <hip/hip_bf16.h>

#define NDIM  4096
#define MROWS 8192
#define PREAL 969
#define KP    1024   // 16 * 64
#define NT    16
#define NWFOLD 1024  // wfold blocks: 16 x 64

typedef unsigned short u16;
typedef __attribute__((ext_vector_type(8))) __bf16 bf16x8;
typedef __attribute__((ext_vector_type(8))) u16 u16x8;
typedef __attribute__((ext_vector_type(4))) float f32x4;

__device__ __forceinline__ u16 bf16rne(float f) {
  unsigned int u = __builtin_bit_cast(unsigned int, f);
  u += 0x7fffu + ((u >> 16) & 1u);
  return (u16)(u >> 16);
}

// -------- compile-time multiset table: TBL.v[p] = (i<<10)|(j<<5)|k, idx 16 = "1"; -1 = pad --------
struct Tbl { int v[KP]; };
constexpr Tbl make_table() {
  Tbl t{};
  for (int p = 0; p < KP; ++p) t.v[p] = -1;
  int p = 0;
  t.v[p++] = (16 << 10) | (16 << 5) | 16;
  for (int i = 0; i < 16; ++i) t.v[p++] = (i << 10) | (16 << 5) | 16;
  for (int i = 0; i < 16; ++i)
    for (int j = i; j < 16; ++j) t.v[p++] = (i << 10) | (j << 5) | 16;
  for (int i = 0; i < 16; ++i)
    for (int j = i; j < 16; ++j)
      for (int k = j; k < 16; ++k) t.v[p++] = (i << 10) | (j << 5) | k;
  return t;
}
__device__ constexpr Tbl TBL = make_table();

// -------- merged prep: blocks [0,NWFOLD) fold W; blocks [NWFOLD, NWFOLD+MROWS) build features --------
__global__ void prep_kernel(const float* __restrict__ z, const float* __restrict__ W,
                            const float* __restrict__ bias,
                            u16* __restrict__ xb, u16* __restrict__ wfbt) {
  __shared__ float tile[64][65];
  __shared__ float zs[17];
  const int bx = blockIdx.x;
  const int tid = threadIdx.x;

  if (bx < NWFOLD) {
    const int p0 = (bx & 15) * 64;
    const int d0 = (bx >> 4) * 64;
    const int d4 = (tid & 15) * 4;
    const int rb = tid >> 4;
    const int dd = d0 + d4;
#pragma unroll
    for (int pp = 0; pp < 4; ++pp) {
      const int r = pp * 16 + rb;
      const int p = p0 + r;
      const int enc = TBL.v[p];
      f32x4 v = {0.f, 0.f, 0.f, 0.f};
      if (enc >= 0) {
        const int i = enc >> 10, j = (enc >> 5) & 31, k = enc & 31;
        if (k == 16) {
          if (j == 16) {
            if (i == 16) {
              v = *reinterpret_cast<const f32x4*>(W + dd);
              f32x4 bb = *reinterpret_cast<const f32x4*>(bias + dd);
              v.x += bb.x; v.y += bb.y; v.z += bb.z; v.w += bb.w;
            } else {
              v = *reinterpret_cast<const f32x4*>(W + (size_t)(1 + i) * NDIM + dd);
            }
          } else {
            v = *reinterpret_cast<const f32x4*>(W + (size_t)(17 + i * 16 + j) * NDIM + dd);
            if (i != j) {
              f32x4 w2 = *reinterpret_cast<const f32x4*>(W + (size_t)(17 + j * 16 + i) * NDIM + dd);
              v.x += w2.x; v.y += w2.y; v.z += w2.z; v.w += w2.w;
            }
          }
        } else {
          int rows[6];
          int nr = 0;
          rows[nr++] = 273 + i * 256 + j * 16 + k;
          if (i == j && j == k) {
          } else if (i == j) {
            rows[nr++] = 273 + i * 256 + k * 16 + i;
            rows[nr++] = 273 + k * 256 + i * 16 + i;
          } else if (j == k) {
            rows[nr++] = 273 + j * 256 + i * 16 + j;
            rows[nr++] = 273 + j * 256 + j * 16 + i;
          } else {
            rows[nr++] = 273 + i * 256 + k * 16 + j;
            rows[nr++] = 273 + j * 256 + i * 16 + k;
            rows[nr++] = 273 + j * 256 + k * 16 + i;
            rows[nr++] = 273 + k * 256 + i * 16 + j;
            rows[nr++] = 273 + k * 256 + j * 16 + i;
          }
          v = *reinterpret_cast<const f32x4*>(W + (size_t)rows[0] * NDIM + dd);
          for (int s = 1; s < nr; ++s) {
            f32x4 w2 = *reinterpret_cast<const f32x4*>(W + (size_t)rows[s] * NDIM + dd);
            v.x += w2.x; v.y += w2.y; v.z += w2.z; v.w += w2.w;
          }
        }
      }
#pragma unroll
      for (int jj = 0; jj < 4; ++jj) tile[r][d4 + jj] = v[jj];
    }
    __syncthreads();
#pragma unroll
    for (int round = 0; round < 2; ++round) {
      const int v = round * 256 + tid;
      const int d = v >> 3;
      const int tg = v & 7;
      u16x8 pack;
#pragma unroll
      for (int e = 0; e < 8; ++e) pack[e] = bf16rne(tile[tg * 8 + e][d]);
      *reinterpret_cast<u16x8*>(wfbt + (size_t)(d0 + d) * KP + p0 + tg * 8) = pack;
    }
  } else {
    const int row = bx - NWFOLD;
    if (tid < 16) zs[tid] = z[row * 16 + tid];
    if (tid == 16) zs[16] = 1.0f;
    __syncthreads();
    u16* xrow = xb + (size_t)row * KP;
    for (int g = tid; g < KP / 8; g += 256) {
      u16x8 pack;
#pragma unroll
      for (int e = 0; e < 8; ++e) {
        const int enc = TBL.v[g * 8 + e];
        float v = 0.0f;
        if (enc >= 0) v = zs[enc >> 10] * (zs[(enc >> 5) & 31] * zs[enc & 31]);
        pack[e] = bf16rne(v);
      }
      *reinterpret_cast<u16x8*>(xrow + g * 8) = pack;
    }
  }
}

// ------- 128x128 tile GEMM, 64 KiB LDS -> 2 blocks/CU (inter-block LDS||MFMA overlap) -------
#define GLOAD(gp, lp)                                                                     \
  __builtin_amdgcn_global_load_lds((const __attribute__((address_space(1))) unsigned int*)(gp), \
                                   (__attribute__((address_space(3))) unsigned int*)(lp), 16, 0, 0)

__device__ __forceinline__ void bar() {
  asm volatile("" ::: "memory");
  __builtin_amdgcn_s_barrier();
  asm volatile("" ::: "memory");
}

#define VM4 asm volatile("s_waitcnt vmcnt(4)" ::: "memory")
#define VM2 asm volatile("s_waitcnt vmcnt(2)" ::: "memory")
#define VM0 asm volatile("s_waitcnt vmcnt(0)" ::: "memory")

__global__ __launch_bounds__(256, 2) void gemm_kernel(const u16* __restrict__ xb,
                                                      const u16* __restrict__ wbt,
                                                      float* __restrict__ out) {
  __shared__ u16 lds[2 * 16384];  // 64 KiB: per buffer A[128][64] + B[128][64]

  // XCD swizzle: 2048 blocks; per XCD 8 M-tiles x 32 N-tiles; concurrent 32-block
  // window covers 4M x 8N (A 1MB + B 2MB < 4MB L2)
  const int bid  = blockIdx.x;
  const int xcd  = bid & 7;
  const int idx  = bid >> 3;            // 0..255 within XCD
  const int win  = idx >> 5;            // 0..7 window
  const int w    = idx & 31;            // 0..31 within window
  const int mtl  = (win >> 2) * 4 + (w >> 3);        // 0..7 local M-tile
  const int ntl  = (win & 3) * 8 + (w & 7);          // 0..31 N-tile
  const int brow = (xcd * 8 + mtl) * 128;
  const int bcol = ntl * 128;

  const int tid  = threadIdx.x;
  const int lane = tid & 63;
  const int wid  = tid >> 6;   // 0..3
  const int wr   = wid >> 1;   // 0..1
  const int wc   = wid & 1;    // 0..1
  const int f    = lane & 15;
  const int q    = lane >> 4;
  const int f7   = f & 7;

  // staging: pre-swizzled global source, linear LDS dest (proven pattern)
  const int lr = lane >> 3;                         // 0..7
  const int swzc = ((lane & 7) ^ lr) * 8;           // pre-swizzled source chunk (u16)
  const u16* gA = xb  + (size_t)(brow + lr) * KP + swzc;
  const u16* gB = wbt + (size_t)(bcol + lr) * KP + swzc;
  // quarter bases: each quarter = 64 rows {0-31, 64-95} (h0) or {32-63, 96-127} (h1);
  // per wave one 16-row group
  const int qB0 = (wid >> 1) * 64 + (wid & 1) * 16;  // h0 base; h1 = +32

#define STGQ(gptr, region, rb, U) do {                                               \
    GLOAD((gptr) + (size_t)(rb) * KP + (U) * 64, (region) + (rb) * 64);              \
    GLOAD((gptr) + (size_t)((rb) + 8) * KP + (U) * 64, (region) + ((rb) + 8) * 64);  \
  } while (0)

// swizzled ds_read_b128 (0-conflict pattern: row low bits = f&7, chunk XOR f7)
#define RD_A(mi, kk) (*reinterpret_cast<const bf16x8*>(bufA + (wr * 64 + (mi) * 16 + f) * 64 + (((kk) * 4 + q) ^ f7) * 8))
#define RD_B(ni, kk) (*reinterpret_cast<const bf16x8*>(bufB + (wc * 64 + (ni) * 16 + f) * 64 + (((kk) * 4 + q) ^ f7) * 8))

#define RDA2(i0) do {                                                                \
    a_[i0][0] = RD_A((i0), 0);     a_[i0][1] = RD_A((i0), 1);                        \
    a_[(i0)+1][0] = RD_A((i0)+1, 0); a_[(i0)+1][1] = RD_A((i0)+1, 1);                \
  } while (0)
#define RDB2(i0) do {                                                                \
    b_[i0][0] = RD_B((i0), 0);     b_[i0][1] = RD_B((i0), 1);                        \
    b_[(i0)+1][0] = RD_B((i0)+1, 0); b_[(i0)+1][1] = RD_B((i0)+1, 1);                \
  } while (0)

// 2 mi x 2 ni x 2 kk = 8 MFMA, setprio-wrapped
#define OCT(M0, N0) do {                                                             \
    __builtin_amdgcn_s_setprio(1);                                                   \
    _Pragma("unroll") for (int _m = 0; _m < 2; ++_m)                                 \
    _Pragma("unroll") for (int _n = 0; _n < 2; ++_n)                                 \
    _Pragma("unroll") for (int _k = 0; _k < 2; ++_k)                                 \
      acc[(M0) + _m][(N0) + _n] = __builtin_amdgcn_mfma_f32_16x16x32_bf16(           \
          a_[(M0) + _m][_k], b_[(N0) + _n][_k], acc[(M0) + _m][(N0) + _n], 0, 0, 0); \
    __builtin_amdgcn_s_setprio(0);                                                   \
  } while (0)

// tile body (R9 fence invariant at 8 loads/tile):
// ph1 reads {a0,a1,b0,b1} (Ah0,Bh0 of t); stage Ah0(t+1); VM4 confirms Bh1(t)
// ph2 reads {b2,b3} (Bh1);               stage Bh0(t+1); VM4 confirms Ah1(t)
// ph3 reads {a2,a3} (Ah1);               stage Bh1(t+1)
// ph4 (reg only);                        stage Ah1(t+1); VM4 confirms Ah0,Bh0(t+1)
#define TILE_BODY(cA, cB, nA, nB, U) do {                                            \
    bufA = (cA); bufB = (cB);                                                        \
    RDA2(0); RDB2(0); STGQ(gA, (nA), qB0, (U));                                      \
    bar(); OCT(0, 0); VM4; bar();                                                    \
    RDB2(2);          STGQ(gB, (nB), qB0, (U));                                      \
    bar(); OCT(0, 2); VM4; bar();                                                    \
    RDA2(2);          STGQ(gB, (nB), qB0 + 32, (U));                                 \
    bar(); OCT(2, 2); bar();                                                         \
                      STGQ(gA, (nA), qB0 + 32, (U));                                 \
    bar(); OCT(2, 0); VM4; bar();                                                    \
  } while (0)

// final tile (no staging): entry outstanding = {Bh1(15), Ah1(15)} = 4 loads
#define TILE_LAST(cA, cB) do {                                                       \
    bufA = (cA); bufB = (cB);                                                        \
    RDA2(0); RDB2(0);                                                                \
    bar(); OCT(0, 0); VM2; bar();                                                    \
    RDB2(2);                                                                         \
    bar(); OCT(0, 2); VM0; bar();                                                    \
    RDA2(2);                                                                         \
    bar(); OCT(2, 2); bar();                                                         \
    OCT(2, 0);                                                                       \
  } while (0)

  f32x4 acc[4][4] = {};
  bf16x8 a_[4][2], b_[4][2];
  const u16 *bufA, *bufB;

  u16* b0A = lds;            u16* b0B = lds + 8192;
  u16* b1A = lds + 16384;    u16* b1B = b1A + 8192;

  // prologue: stage tile0's quarters in read order (Ah0, Bh0, Bh1, Ah1);
  // VM4 -> Ah0,Bh0 resident, Bh1+Ah1 in flight
  STGQ(gA, b0A, qB0, 0); STGQ(gB, b0B, qB0, 0);
  STGQ(gB, b0B, qB0 + 32, 0); STGQ(gA, b0A, qB0 + 32, 0);
  VM4; bar();

  for (int t = 0; t < NT - 2; t += 2) {             // tiles 0..13
    TILE_BODY(b0A, b0B, b1A, b1B, t + 1);
    TILE_BODY(b1A, b1B, b0A, b0B, t + 2);
  }
  TILE_BODY(b0A, b0B, b1A, b1B, NT - 1);            // tile 14: stages tile 15 -> buf1
  TILE_LAST(b1A, b1B);                              // tile 15

  // epilogue: plain cached stores; C/D layout col = lane&15, row = (lane>>4)*4 + j
  const int r0 = brow + wr * 64 + q * 4;
  const int c0 = bcol + wc * 64 + f;
#pragma unroll
  for (int mi = 0; mi < 4; ++mi)
#pragma unroll
    for (int ni = 0; ni < 4; ++ni) {
#pragma unroll
      for (int j = 0; j < 4; ++j)
        out[(size_t)(r0 + mi * 16 + j) * NDIM + (c0 + ni * 16)] = acc[mi][ni][j];
    }
}

// ---------------- fallback (ws too small): correct fp32 path on raw features ----------------
__global__ void fallback_kernel(const float* __restrict__ z, const float* __restrict__ W,
                                const float* __restrict__ bias, float* __restrict__ out) {
  __shared__ float feat[4369];
  const int row = blockIdx.x;
  const int tid = threadIdx.x;
  for (int t = tid; t < 4369; t += 256) {
    float v;
    if (t == 0) v = 1.0f;
    else if (t < 17) v = z[row * 16 + t - 1];
    else if (t < 273) { int u = t - 17; v = z[row * 16 + (u >> 4)] * z[row * 16 + (u & 15)]; }
    else { int u = t - 273; v = z[row * 16 + ((u >> 8) & 15)] * (z[row * 16 + ((u >> 4) & 15)] * z[row * 16 + (u & 15)]); }
    feat[t] = v;
  }
  __syncthreads();
  float acc[16];
#pragma unroll
  for (int j = 0; j < 16; ++j) acc[j] = bias[tid + 256 * j];
  for (int t = 0; t < 4369; ++t) {
    const float fv = feat[t];
    const float* wrow = W + (size_t)t * NDIM;
#pragma unroll
    for (int j = 0; j < 16; ++j) acc[j] = fmaf(fv, wrow[tid + 256 * j], acc[j]);
  }
  float* orow = out + (size_t)row * NDIM;
#pragma unroll
  for (int j = 0; j < 16; ++j) orow[tid + 256 * j] = acc[j];
}

extern "C" void kernel_launch(void* const* d_in, const int* in_sizes, int n_in,
                              void* d_out, int out_size, void* d_ws, size_t ws_size,
                              hipStream_t stream) {
  const float* z = (const float*)d_in[0];
  const float* W = (const float*)d_in[1];
  const float* b = (const float*)d_in[2];
  float* out = (float*)d_out;

  const size_t xb_elems  = (size_t)MROWS * KP;
  const size_t wbt_elems = (size_t)NDIM * KP;
  const size_t need = (xb_elems + wbt_elems) * sizeof(u16);

  if (ws_size >= need) {
    u16* xb  = (u16*)d_ws;
    u16* wbt = xb + xb_elems;
    prep_kernel<<<NWFOLD + MROWS, 256, 0, stream>>>(z, W, b, xb, wbt);
    gemm_kernel<<<(MROWS / 128) * (NDIM / 128), 256, 0, stream>>>(xb, wbt, out);
  } else {
    fallback_kernel<<<MROWS, 256, 0, stream>>>(z, W, b, out);
  }
}